// Round 12
// baseline (148.003 us; speedup 1.0000x reference)
//
#include <hip/hip_runtime.h>
#include <hip/hip_bf16.h>

#define NV 40962
#define NK 9
#define CIN 32
#define COUT 32
#define NBS 4
#define VT 256                 // transpose v-tile
#define TP 260                 // transpose LDS row stride (dwords)
#define NT 2561                // v-tiles of 16 in main kernel
#define NV81 (NV * 81)
#define NV9  (NV * 9)

typedef __attribute__((ext_vector_type(8))) short bf16x8;
typedef __attribute__((ext_vector_type(4))) float f32x4;

// f32 pair -> packed bf16 dword (a=low), via v_cvt_pk_bf16_f32 (RNE)
__device__ __forceinline__ unsigned pkbf(float a, float b) {
    union { __hip_bfloat162 h2; unsigned u; } cv;
    cv.h2 = __float22bfloat162_rn(make_float2(a, b));
    return cv.u;
}

// ---------------------------------------------------------------------------
// Kernel 1: x [128 rows=(b*32+c)][V] f32 -> xt [v][b0|b1|b2|b3 x 32ch] bf16
// (256 B/row; one row serves all 4 batches of a gather).
// ---------------------------------------------------------------------------
__global__ void __launch_bounds__(256) transpose_x_bf16(
    const float* __restrict__ x, unsigned* __restrict__ xtw)
{
    __shared__ unsigned T[16 * TP];
    const int b  = blockIdx.x & 3;
    const int v0 = (blockIdx.x >> 2) * VT;
    const int t  = threadIdx.x;
    const int w  = t >> 6;
    const int L  = t & 63;
    const bool full = (v0 + VT <= NV);

    #pragma unroll
    for (int i = 0; i < 4; ++i) {
        const int q = w + 4 * i;             // ch-pair 0..15 (ch 2q, 2q+1)
        const float* rowA = x + (size_t)(b * 32 + 2 * q) * NV;
        const float* rowB = rowA + NV;
        #pragma unroll
        for (int h = 0; h < 2; ++h) {
            const int vl = 128 * h + 2 * L;
            float2 a, c;
            if (full) {
                a = *(const float2*)(rowA + v0 + vl);
                c = *(const float2*)(rowB + v0 + vl);
            } else {
                const int v = v0 + vl;
                a.x = (v     < NV) ? rowA[v]     : 0.0f;
                a.y = (v + 1 < NV) ? rowA[v + 1] : 0.0f;
                c.x = (v     < NV) ? rowB[v]     : 0.0f;
                c.y = (v + 1 < NV) ? rowB[v + 1] : 0.0f;
            }
            uint2 d;
            d.x = pkbf(a.x, c.x);
            d.y = pkbf(a.y, c.y);
            *(uint2*)&T[q * TP + vl] = d;
        }
    }
    __syncthreads();

    #pragma unroll
    for (int i = 0; i < 4; ++i) {
        const int vl = i * 64 + w * 16 + (L >> 2);
        const int u4 = L & 3;
        const int v  = v0 + vl;
        if (v < NV) {
            uint4 d;
            d.x = T[(4 * u4 + 0) * TP + vl];
            d.y = T[(4 * u4 + 1) * TP + vl];
            d.z = T[(4 * u4 + 2) * TP + vl];
            d.w = T[(4 * u4 + 3) * TP + vl];
            *(uint4*)&xtw[(size_t)v * 64 + b * 16 + 4 * u4] = d;
        }
    }
}

// ---------------------------------------------------------------------------
// Kernel 2: conv weight f32 [o][c][j] -> bf16 [o][k=c*9+j]  (GEMM K-order)
// ---------------------------------------------------------------------------
__global__ void __launch_bounds__(256) convert_w_bf16(
    const float* __restrict__ w, unsigned short* __restrict__ wbf)
{
    const int i = blockIdx.x * 256 + threadIdx.x;
    if (i < COUT * CIN * NK) {
        unsigned u = __float_as_uint(w[i]);
        wbf[i] = (unsigned short)((u + 0x7FFFu + ((u >> 16) & 1u)) >> 16);
    }
}

// ---------------------------------------------------------------------------
// Kernel 3: wave-autonomous fused kernel. Non-persistent: block = one
// 16-vertex tile (grid = 2561), 256 thr = 4 waves, wave q = batch q.
// ONE __syncthreads (after cooperative itp/idx staging); afterwards each
// wave runs free: own gathers, private Alds slot, W-frags from global
// (L1-hot 18KB), in-wave shfl nz-reduce, masked stores. No inter-wave
// convoys — each wave stalls only on its own loads; 12 waves/CU (3 blocks
// x 43.8KB LDS) interleave across VALU/LDS/TA/MFMA pipes.
// Lane = (vloc = lane&15, quad = lane>>4); quad = 8-ch group in interp,
// K-quad/o-subrow in MFMA (matches A/B/C fragment layouts).
// ---------------------------------------------------------------------------
__global__ void __launch_bounds__(256) sparse_conv_mfma(
    const unsigned short* __restrict__ xt, const int* __restrict__ index,
    const float* __restrict__ itp, const unsigned short* __restrict__ wbf,
    const float* __restrict__ bias, float* __restrict__ out)
{
    __shared__ unsigned Alds[4][72 * 16 * 2];   // 4 x 9216 B, wave-private
    __shared__ float itp_s[16 * 108];           // 6912 B, read-only after bar
    __shared__ int   idx_s[144];                //  576 B, read-only after bar

    const int t    = threadIdx.x;
    const int q    = t >> 6;                 // wave = batch
    const int lane = t & 63;
    const int vloc = lane & 15;
    const int quad = lane >> 4;
    const int tile = blockIdx.x;
    const int v0   = tile * 16;

    // ---- cooperative staging + the kernel's single barrier ----
    if (t < 144) {
        const size_t bix = (size_t)tile * 144 + t;
        idx_s[t] = (bix < (size_t)NV9) ? index[bix] : 0;
    }
    {
        float itpv[6];
        const size_t base = (size_t)tile * 1296;
        #pragma unroll
        for (int i = 0; i < 6; ++i) {
            const int o = i * 256 + t;
            itpv[i] = (o < 1296 && base + o < (size_t)NV81) ? itp[base + o]
                                                            : 0.0f;
        }
        #pragma unroll
        for (int i = 0; i < 6; ++i) {        // padded [vl][k][12] rows
            const int o = i * 256 + t;
            if (o < 1296) {
                const int vl = o / 81;
                const int r  = o - vl * 81;
                const int kk = r / 9;
                const int jj = r - kk * 9;
                itp_s[vl * 108 + kk * 12 + jj] = itpv[i];
            }
        }
    }
    __syncthreads();                         // waves independent after this

    // ---- my neighbor ids (quad-redundant broadcast reads) ----
    int nbr[NK];
    #pragma unroll
    for (int k = 0; k < NK; ++k) nbr[k] = idx_s[vloc * 9 + k];

    // ---- issue all 18 gathers up-front (lane covers ch quad*8+h*4..+4) ----
    const unsigned short* gb = xt + q * 32 + quad * 8;
    uint2 g0[NK], g1[NK];
    #pragma unroll
    for (int k = 0; k < NK; ++k)
        g0[k] = *(const uint2*)(gb + (size_t)nbr[k] * 128);
    #pragma unroll
    for (int k = 0; k < NK; ++k)
        g1[k] = *(const uint2*)(gb + (size_t)nbr[k] * 128 + 4);

    // ---- interp + pack, half-channels at a time (acc regs reused) ----
    unsigned nzbits = 0;
    #pragma unroll
    for (int h = 0; h < 2; ++h) {
        float acc[4][NK];
        #pragma unroll
        for (int cc = 0; cc < 4; ++cc)
            #pragma unroll
            for (int j = 0; j < NK; ++j) acc[cc][j] = 0.0f;
        #pragma unroll
        for (int k = 0; k < NK; ++k) {
            const uint2 gk = h ? g1[k] : g0[k];
            nzbits |= (gk.x | gk.y) & 0x7FFF7FFFu;
            const float f0 = __uint_as_float(gk.x << 16);
            const float f1 = __uint_as_float(gk.x & 0xFFFF0000u);
            const float f2 = __uint_as_float(gk.y << 16);
            const float f3 = __uint_as_float(gk.y & 0xFFFF0000u);
            const float* ir = &itp_s[vloc * 108 + k * 12];
            const float4 ra = *(const float4*)ir;
            const float4 rb = *(const float4*)(ir + 4);
            const float  rc = ir[8];
            const float row[NK] = {ra.x, ra.y, ra.z, ra.w,
                                   rb.x, rb.y, rb.z, rb.w, rc};
            #pragma unroll
            for (int j = 0; j < NK; ++j) {
                acc[0][j] += f0 * row[j];
                acc[1][j] += f1 * row[j];
                acc[2][j] += f2 * row[j];
                acc[3][j] += f3 * row[j];
            }
        }
        // pack lane's k-range [quad*72+h*36, +36) into plane layout
        // plane = k/4 = quad*18 + h*9 + i2 ; addr (plane*16+vloc)*2 dwords
        #pragma unroll
        for (int i2 = 0; i2 < 9; ++i2) {
            const int k0 = 4 * i2;           // local k within the 36
            const int pl = quad * 18 + h * 9 + i2;
            uint2 d;
            d.x = pkbf(acc[k0 / 9][k0 % 9],
                       acc[(k0 + 1) / 9][(k0 + 1) % 9]);
            d.y = pkbf(acc[(k0 + 2) / 9][(k0 + 2) % 9],
                       acc[(k0 + 3) / 9][(k0 + 3) % 9]);
            *(uint2*)&Alds[q][(pl * 16 + vloc) * 2] = d;
        }
    }

    // ---- nz mask: OR over all 32 channels = over the 4 quads, in-wave ----
    unsigned nzw = nzbits;
    nzw |= __shfl_xor(nzw, 16);
    nzw |= __shfl_xor(nzw, 32);

    // ---- MFMA: 9 K-steps x 2 o-halves; A from global wbf (L1-hot) ----
    f32x4 c0 = {0.f, 0.f, 0.f, 0.f};
    f32x4 c1 = {0.f, 0.f, 0.f, 0.f};
    #pragma unroll
    for (int ks = 0; ks < NK; ++ks) {
        const int p0 = ks * 8 + quad * 2;
        const uint2 lo = *(const uint2*)&Alds[q][(p0 * 16 + vloc) * 2];
        const uint2 hi = *(const uint2*)&Alds[q][((p0 + 1) * 16 + vloc) * 2];
        union { uint4 u; bf16x8 v; } bf;
        bf.u.x = lo.x; bf.u.y = lo.y; bf.u.z = hi.x; bf.u.w = hi.y;
        const int ko = ks * 32 + quad * 8;
        const bf16x8 wa0 = *(const bf16x8*)(wbf + vloc * 288 + ko);
        const bf16x8 wa1 = *(const bf16x8*)(wbf + (vloc + 16) * 288 + ko);
        c0 = __builtin_amdgcn_mfma_f32_16x16x32_bf16(wa0, bf.v, c0, 0, 0, 0);
        c1 = __builtin_amdgcn_mfma_f32_16x16x32_bf16(wa1, bf.v, c1, 0, 0, 0);
    }

    // ---- epilogue: C row = quad*4+r, col = vloc ----
    const int vv = v0 + vloc;
    if (vv < NV) {
        const float m = nzw ? 1.0f : 0.0f;
        float* ob = out + (size_t)q * (COUT * NV) + vv;
        #pragma unroll
        for (int r = 0; r < 4; ++r) {
            const int o = quad * 4 + r;
            ob[(size_t)o * NV]        = (c0[r] + bias[o]) * m;
            ob[(size_t)(o + 16) * NV] = (c1[r] + bias[o + 16]) * m;
        }
    }
}

// ---------------------------------------------------------------------------
extern "C" void kernel_launch(void* const* d_in, const int* in_sizes, int n_in,
                              void* d_out, int out_size, void* d_ws, size_t ws_size,
                              hipStream_t stream)
{
    const float* x     = (const float*)d_in[0];
    const int*   index = (const int*)  d_in[1];
    const float* itp   = (const float*)d_in[2];
    const float* w     = (const float*)d_in[3];
    const float* bias  = (const float*)d_in[4];
    float*       out   = (float*)d_out;

    unsigned short* xt  = (unsigned short*)d_ws;                 // 10.5 MB
    unsigned short* wbf = (unsigned short*)((char*)d_ws + (size_t)NV * 256);

    hipLaunchKernelGGL(convert_w_bf16, dim3((COUT * CIN * NK + 255) / 256),
                       dim3(256), 0, stream, w, wbf);
    const int vtiles = (NV + VT - 1) / VT;   // 161
    hipLaunchKernelGGL(transpose_x_bf16, dim3(vtiles * NBS), dim3(256), 0,
                       stream, x, (unsigned*)xt);
    hipLaunchKernelGGL(sparse_conv_mfma, dim3(NT), dim3(256), 0,
                       stream, xt, index, itp, wbf, bias, out);
}

// Round 13
// 129.861 us; speedup vs baseline: 1.1397x; 1.1397x over previous
//
#include <hip/hip_runtime.h>
#include <hip/hip_bf16.h>

#define NV 40962
#define NK 9
#define CIN 32
#define COUT 32
#define NBS 4
#define VT 256                 // transpose v-tile
#define TP 260                 // transpose LDS row stride (dwords)
#define NT 2561                // v-tiles of 16 in main kernel
#define PGRID 512              // persistent blocks (2 per CU, all co-resident)
#define NV81 (NV * 81)
#define NV9  (NV * 9)

typedef __attribute__((ext_vector_type(8))) short bf16x8;
typedef __attribute__((ext_vector_type(4))) float f32x4;
typedef __attribute__((ext_vector_type(2))) float f32x2;

// ---- packed f32 FMA/MUL with src0 broadcast from pair half (VOP3P op_sel).
// _L: both result halves use src0.lo ; _H: both use src0.hi.
// src1 (row pair) and src2/dst (acc pair) are normal packed operands.
#define PKFMA_L(A, G, R) asm("v_pk_fma_f32 %0, %1, %2, %0 op_sel:[0,0,0] op_sel_hi:[0,1,1]" : "+v"(A) : "v"(G), "v"(R))
#define PKFMA_H(A, G, R) asm("v_pk_fma_f32 %0, %1, %2, %0 op_sel:[1,0,0] op_sel_hi:[1,1,1]" : "+v"(A) : "v"(G), "v"(R))
#define PKMUL_L(A, G, R) asm("v_pk_mul_f32 %0, %1, %2 op_sel:[0,0] op_sel_hi:[0,1]" : "=v"(A) : "v"(G), "v"(R))
#define PKMUL_H(A, G, R) asm("v_pk_mul_f32 %0, %1, %2 op_sel:[1,0] op_sel_hi:[1,1]" : "=v"(A) : "v"(G), "v"(R))

// acc element access with compile-time (cc,j): j<8 in pairs, j=8 scalar
#define ACC(cc, j) ((j) == 8 ? acc8[cc] : (((j) & 1) ? acc2[cc][(j) >> 1].y \
                                                     : acc2[cc][(j) >> 1].x))

// f32 pair -> packed bf16 dword (a=low), via v_cvt_pk_bf16_f32 (RNE)
__device__ __forceinline__ unsigned pkbf(float a, float b) {
    union { __hip_bfloat162 h2; unsigned u; } cv;
    cv.h2 = __float22bfloat162_rn(make_float2(a, b));
    return cv.u;
}

// LDS-only barrier (no vmcnt drain): cross-wave data here moves via ds_write;
// in-flight global loads are register-consumed by their issuing wave.
__device__ __forceinline__ void bar_lgkm() {
    asm volatile("s_waitcnt lgkmcnt(0)\n\ts_barrier" ::: "memory");
}

// ---------------------------------------------------------------------------
// Kernel 1: x [128 rows=(b*32+c)][V] f32 -> xt [v][b0|b1|b2|b3 x 32ch] bf16
// (256 B/row; one row serves all 4 batches of a gather).
// ---------------------------------------------------------------------------
__global__ void __launch_bounds__(256) transpose_x_bf16(
    const float* __restrict__ x, unsigned* __restrict__ xtw)
{
    __shared__ unsigned T[16 * TP];
    const int b  = blockIdx.x & 3;
    const int v0 = (blockIdx.x >> 2) * VT;
    const int t  = threadIdx.x;
    const int w  = t >> 6;
    const int L  = t & 63;
    const bool full = (v0 + VT <= NV);

    #pragma unroll
    for (int i = 0; i < 4; ++i) {
        const int q = w + 4 * i;             // ch-pair 0..15 (ch 2q, 2q+1)
        const float* rowA = x + (size_t)(b * 32 + 2 * q) * NV;
        const float* rowB = rowA + NV;
        #pragma unroll
        for (int h = 0; h < 2; ++h) {
            const int vl = 128 * h + 2 * L;
            float2 a, c;
            if (full) {
                a = *(const float2*)(rowA + v0 + vl);
                c = *(const float2*)(rowB + v0 + vl);
            } else {
                const int v = v0 + vl;
                a.x = (v     < NV) ? rowA[v]     : 0.0f;
                a.y = (v + 1 < NV) ? rowA[v + 1] : 0.0f;
                c.x = (v     < NV) ? rowB[v]     : 0.0f;
                c.y = (v + 1 < NV) ? rowB[v + 1] : 0.0f;
            }
            uint2 d;
            d.x = pkbf(a.x, c.x);
            d.y = pkbf(a.y, c.y);
            *(uint2*)&T[q * TP + vl] = d;
        }
    }
    __syncthreads();

    #pragma unroll
    for (int i = 0; i < 4; ++i) {
        const int vl = i * 64 + w * 16 + (L >> 2);
        const int u4 = L & 3;
        const int v  = v0 + vl;
        if (v < NV) {
            uint4 d;
            d.x = T[(4 * u4 + 0) * TP + vl];
            d.y = T[(4 * u4 + 1) * TP + vl];
            d.z = T[(4 * u4 + 2) * TP + vl];
            d.w = T[(4 * u4 + 3) * TP + vl];
            *(uint4*)&xtw[(size_t)v * 64 + b * 16 + 4 * u4] = d;
        }
    }
}

// itp global load for a 16-vertex tile (1296 dwords), per-element guarded.
__device__ __forceinline__ void load_itp(float itpv[3],
                                         const float* __restrict__ itp,
                                         int tile, int t)
{
    const size_t base = (size_t)tile * 1296;
    #pragma unroll
    for (int i = 0; i < 3; ++i) {
        const int o = i * 512 + t;
        itpv[i] = (o < 1296 && base + o < (size_t)NV81) ? itp[base + o] : 0.0f;
    }
}

// stage 1296 itp dwords into padded LDS [vl][k][12]
__device__ __forceinline__ void stage_itp(float* __restrict__ buf,
                                          const float itpv[3], int t)
{
    #pragma unroll
    for (int i = 0; i < 3; ++i) {
        const int o = i * 512 + t;
        if (o < 1296) {
            const int vl = o / 81;
            const int r  = o - vl * 81;
            const int kk = r / 9;
            const int jj = r - kk * 9;
            buf[vl * 108 + kk * 12 + jj] = itpv[i];
        }
    }
}

// idx global load for a tile (144 ints via threads t<144), guarded
__device__ __forceinline__ int load_idx(const int* __restrict__ index,
                                        int tile, int t)
{
    int r = 0;
    if (t < 144) {
        const size_t base = (size_t)tile * 144 + t;
        r = (base < (size_t)NV9) ? index[base] : 0;
    }
    return r;
}

// ---------------------------------------------------------------------------
// Kernel 2: persistent pipelined fused kernel (r11 structure), 512 thr, 2/CU.
// r13 change: interp inner product on v_pk_fma_f32 (packed 2xf32, pairs over
// j; channel scalar broadcast from unpack-pair halves via op_sel) -- 36
// scalar FMA/k -> 16 pk + 4 scalar; k=0 via v_pk_mul (no acc zero-init).
// ---------------------------------------------------------------------------
__global__ void __launch_bounds__(512) sparse_conv_mfma(
    const unsigned short* __restrict__ xt, const int* __restrict__ index,
    const float* __restrict__ itp, const float* __restrict__ w,
    const float* __restrict__ bias, float* __restrict__ out)
{
    __shared__ unsigned Alds8[72 * 64 * 2];        // 36864 B: plane h = k 4h..4h+3
    __shared__ unsigned short Wlds[36 * 32 * 8];   // 18432 B
    __shared__ float itp_s[16 * 108];              //  6912 B
    __shared__ int   idx_s[2][144];                //  1152 B
    __shared__ unsigned long long nzb[8];          //    64 B

    const int t    = threadIdx.x;
    const int col  = t & 63;                 // b*16 + vloc (lane id)
    const int q    = t >> 6;                 // wave id; ch-group c = 4q..4q+3
    const int b    = col >> 4;               // batch in B; K-quad in D
    const int vloc = col & 15;
    const unsigned short* gb = xt + b * 32 + q * 4;

    // ---------------- prologue ----------------
    int tile = blockIdx.x;

    // stage W: chunk ch holds W[o][ch*8 .. ch*8+8) as 16B per o
    #pragma unroll
    for (int r = 0; r < 3; ++r) {
        const int j = t + r * 512;
        if (j < 1152) {
            const int o = j & 31;
            const int c = j >> 5;
            const float4 f0 = *(const float4*)(w + o * 288 + c * 8);
            const float4 f1 = *(const float4*)(w + o * 288 + c * 8 + 4);
            uint4 d;
            d.x = pkbf(f0.x, f0.y); d.y = pkbf(f0.z, f0.w);
            d.z = pkbf(f1.x, f1.y); d.w = pkbf(f1.z, f1.w);
            *(uint4*)&Wlds[(c * 32 + o) * 8] = d;
        }
    }
    {
        const int i0 = load_idx(index, tile, t);
        const int i1 = load_idx(index, min(tile + PGRID, NT - 1), t);
        if (t < 144) { idx_s[0][t] = i0; idx_s[1][t] = i1; }
    }
    float itpv[3];
    load_itp(itpv, itp, tile, t);
    stage_itp(itp_s, itpv, t);
    __syncthreads();                         // Wlds/idx_s/itp_s visible

    uint2 gath[NK];
    #pragma unroll
    for (int k = 0; k < NK; ++k) {           // gathers(t0)
        const int nbr = idx_s[0][vloc * 9 + k];
        gath[k] = *(const uint2*)(gb + (size_t)nbr * 128);
    }
    load_itp(itpv, itp, min(tile + PGRID, NT - 1), t);
    int idxn = load_idx(index, min(tile + 2 * PGRID, NT - 1), t);
    int cur = 0;

    for (; tile < NT; tile += PGRID) {
        // ---- B: consume gath(t)+itp_s -> interp; interleave gath(t+1) issue
        unsigned nzbits = 0;
        f32x2 acc2[4][4];                    // [cc][j-pair]
        float acc8[4];                       // j = 8
        const float* ib = &itp_s[vloc * 108];

        #pragma unroll
        for (int k = 0; k < 4; ++k) {
            const uint2 gk = gath[k];
            nzbits |= (gk.x | gk.y) & 0x7FFF7FFFu;
            f32x2 gp01, gp23;
            gp01.x = __uint_as_float(gk.x << 16);
            gp01.y = __uint_as_float(gk.x & 0xFFFF0000u);
            gp23.x = __uint_as_float(gk.y << 16);
            gp23.y = __uint_as_float(gk.y & 0xFFFF0000u);
            const float* ir = ib + k * 12;
            f32x2 rp[4];
            rp[0] = *(const f32x2*)ir;       rp[1] = *(const f32x2*)(ir + 2);
            rp[2] = *(const f32x2*)(ir + 4); rp[3] = *(const f32x2*)(ir + 6);
            const float r8 = ir[8];
            if (k == 0) {
                #pragma unroll
                for (int jp = 0; jp < 4; ++jp) {
                    PKMUL_L(acc2[0][jp], gp01, rp[jp]);
                    PKMUL_H(acc2[1][jp], gp01, rp[jp]);
                    PKMUL_L(acc2[2][jp], gp23, rp[jp]);
                    PKMUL_H(acc2[3][jp], gp23, rp[jp]);
                }
                acc8[0] = gp01.x * r8; acc8[1] = gp01.y * r8;
                acc8[2] = gp23.x * r8; acc8[3] = gp23.y * r8;
            } else {
                #pragma unroll
                for (int jp = 0; jp < 4; ++jp) {
                    PKFMA_L(acc2[0][jp], gp01, rp[jp]);
                    PKFMA_H(acc2[1][jp], gp01, rp[jp]);
                    PKFMA_L(acc2[2][jp], gp23, rp[jp]);
                    PKFMA_H(acc2[3][jp], gp23, rp[jp]);
                }
                acc8[0] += gp01.x * r8; acc8[1] += gp01.y * r8;
                acc8[2] += gp23.x * r8; acc8[3] += gp23.y * r8;
            }
        }
        #pragma unroll
        for (int k = 0; k < 4; ++k) {        // reissue k0-3 early
            const int nbr = idx_s[cur ^ 1][vloc * 9 + k];
            gath[k] = *(const uint2*)(gb + (size_t)nbr * 128);
        }
        #pragma unroll
        for (int k = 4; k < 9; ++k) {
            const uint2 gk = gath[k];
            nzbits |= (gk.x | gk.y) & 0x7FFF7FFFu;
            f32x2 gp01, gp23;
            gp01.x = __uint_as_float(gk.x << 16);
            gp01.y = __uint_as_float(gk.x & 0xFFFF0000u);
            gp23.x = __uint_as_float(gk.y << 16);
            gp23.y = __uint_as_float(gk.y & 0xFFFF0000u);
            const float* ir = ib + k * 12;
            f32x2 rp[4];
            rp[0] = *(const f32x2*)ir;       rp[1] = *(const f32x2*)(ir + 2);
            rp[2] = *(const f32x2*)(ir + 4); rp[3] = *(const f32x2*)(ir + 6);
            const float r8 = ir[8];
            #pragma unroll
            for (int jp = 0; jp < 4; ++jp) {
                PKFMA_L(acc2[0][jp], gp01, rp[jp]);
                PKFMA_H(acc2[1][jp], gp01, rp[jp]);
                PKFMA_L(acc2[2][jp], gp23, rp[jp]);
                PKFMA_H(acc2[3][jp], gp23, rp[jp]);
            }
            acc8[0] += gp01.x * r8; acc8[1] += gp01.y * r8;
            acc8[2] += gp23.x * r8; acc8[3] += gp23.y * r8;
        }
        #pragma unroll
        for (int k = 4; k < 9; ++k) {
            const int nbr = idx_s[cur ^ 1][vloc * 9 + k];
            gath[k] = *(const uint2*)(gb + (size_t)nbr * 128);
        }

        // pack: thread's k = 36q+4*i2 .. +4 -> plane h = 9q+i2 (8B per col)
        #pragma unroll
        for (int i2 = 0; i2 < 9; ++i2) {
            const int k0 = 4 * i2;
            const int h  = 9 * q + i2;
            uint2 d;
            d.x = pkbf(ACC(k0 / 9, k0 % 9),
                       ACC((k0 + 1) / 9, (k0 + 1) % 9));
            d.y = pkbf(ACC((k0 + 2) / 9, (k0 + 2) % 9),
                       ACC((k0 + 3) / 9, (k0 + 3) % 9));
            *(uint2*)&Alds8[(h * 64 + col) * 2] = d;
        }
        const unsigned long long bal = __ballot(nzbits != 0);
        if (col == 0) nzb[q] = bal;

        bar_lgkm();                          // E1: Alds8/nzb visible

        // ---- D: MFMA + store; pipeline maintenance ----
        {
            const int dq = b;                // K-quad
            const int bb = q >> 1;
            const int oh = q & 1;
            const int colw = bb * 16 + vloc;

            f32x4 a0 = {0.f, 0.f, 0.f, 0.f};
            #pragma unroll
            for (int ks = 0; ks < 9; ++ks) {
                const int h0 = ks * 8 + dq * 2;
                const uint2 l2 = *(const uint2*)&Alds8[(h0 * 64 + colw) * 2];
                const uint2 h2 = *(const uint2*)&Alds8[((h0 + 1) * 64 + colw) * 2];
                union { uint4 u; bf16x8 v; } f;
                f.u.x = l2.x; f.u.y = l2.y; f.u.z = h2.x; f.u.w = h2.y;
                const int ch = ks * 4 + dq;
                const bf16x8 wa = *(const bf16x8*)&Wlds[(ch * 32 + oh * 16 + vloc) * 8];
                a0 = __builtin_amdgcn_mfma_f32_16x16x32_bf16(wa, f.v, a0, 0, 0, 0);
            }

            const unsigned long long nz = nzb[0] | nzb[1] | nzb[2] | nzb[3] |
                                          nzb[4] | nzb[5] | nzb[6] | nzb[7];
            const float m = ((nz >> colw) & 1ull) ? 1.0f : 0.0f;
            const int vv = tile * 16 + vloc;
            if (vv < NV) {
                float* outb = out + (size_t)bb * (COUT * NV) + vv;
                #pragma unroll
                for (int r = 0; r < 4; ++r) {
                    const int o = oh * 16 + dq * 4 + r;
                    outb[(size_t)o * NV] = (a0[r] + bias[o]) * m;
                }
            }
        }
        stage_itp(itp_s, itpv, t);           // itp(t+1); safe after E1
        if (t < 144) idx_s[cur][t] = idxn;   // idx(t+2)
        load_itp(itpv, itp, min(tile + 2 * PGRID, NT - 1), t);
        idxn = load_idx(index, min(tile + 3 * PGRID, NT - 1), t);

        bar_lgkm();                          // E2: Alds reads done before reuse
        cur ^= 1;
    }
}

// ---------------------------------------------------------------------------
extern "C" void kernel_launch(void* const* d_in, const int* in_sizes, int n_in,
                              void* d_out, int out_size, void* d_ws, size_t ws_size,
                              hipStream_t stream)
{
    const float* x     = (const float*)d_in[0];
    const int*   index = (const int*)  d_in[1];
    const float* itp   = (const float*)d_in[2];
    const float* w     = (const float*)d_in[3];
    const float* bias  = (const float*)d_in[4];
    float*       out   = (float*)d_out;

    unsigned short* xt = (unsigned short*)d_ws;     // NV*256 B = 10.5 MB

    const int vtiles = (NV + VT - 1) / VT;   // 161
    hipLaunchKernelGGL(transpose_x_bf16, dim3(vtiles * NBS), dim3(256), 0,
                       stream, x, (unsigned*)xt);
    hipLaunchKernelGGL(sparse_conv_mfma, dim3(PGRID), dim3(512), 0,
                       stream, xt, index, itp, w, bias, out);
}